// Round 12
// baseline (747.639 us; speedup 1.0000x reference)
//
#include <hip/hip_runtime.h>
#include <hip/hip_bf16.h>

#define NB 4
#define NN 2048
#define FIN 64
#define DOUT 128

typedef __hip_bfloat16 bf16;
typedef __attribute__((ext_vector_type(8))) short short8;
typedef __attribute__((ext_vector_type(4))) float f32x4;
typedef __attribute__((ext_vector_type(4))) int int4v;

static __device__ __forceinline__ float bf2f(bf16 v) { return __bfloat162float(v); }
static __device__ __forceinline__ bf16  f2bf(float v) { return __float2bfloat16(v); }
static __device__ __forceinline__ unsigned bfbits(float v) {
    bf16 h = __float2bfloat16(v);
    return (unsigned)*reinterpret_cast<unsigned short*>(&h);
}

// ---------------- Kernel 1: q1,k1 (bf16), vT (bf16 transposed), proj (bf16) ----------------
__global__ __launch_bounds__(256) void k_gemm1(
    const float* __restrict__ x,
    const float* __restrict__ q1w, const float* __restrict__ q1b,
    const float* __restrict__ k1w, const float* __restrict__ k1b,
    const float* __restrict__ v1w, const float* __restrict__ v1b,
    const float* __restrict__ pw,
    bf16* __restrict__ qA, bf16* __restrict__ kA, bf16* __restrict__ vT,
    bf16* __restrict__ projb)
{
    __shared__ float At[64][65];
    __shared__ float Wt[64][65];
    const int rb = blockIdx.x;
    const int cb = blockIdx.y;
    const int mat = cb >> 1;
    const int c0 = (cb & 1) * 64;
    const float* W    = (mat==0)? q1w : (mat==1)? k1w : (mat==2)? v1w : pw;
    const float* bias = (mat==0)? q1b : (mat==1)? k1b : (mat==2)? v1b : nullptr;
    const int t = threadIdx.x;
    const int row0 = rb * 64;
    for (int e = t; e < 64*64; e += 256) {
        int r = e >> 6, c = e & 63;
        At[r][c] = x[(size_t)(row0 + r)*FIN + c];
        Wt[r][c] = W[r*DOUT + c0 + c];
    }
    __syncthreads();
    const int ty = t >> 4, tx = t & 15;
    float acc[4][4] = {};
    #pragma unroll 8
    for (int k = 0; k < 64; ++k) {
        float av[4], bv[4];
        #pragma unroll
        for (int i = 0; i < 4; ++i) av[i] = At[ty*4+i][k];
        #pragma unroll
        for (int j = 0; j < 4; ++j) bv[j] = Wt[k][tx*4+j];
        #pragma unroll
        for (int i = 0; i < 4; ++i)
            #pragma unroll
            for (int j = 0; j < 4; ++j)
                acc[i][j] = fmaf(av[i], bv[j], acc[i][j]);
    }
    #pragma unroll
    for (int i = 0; i < 4; ++i) {
        int gr = row0 + ty*4 + i;
        #pragma unroll
        for (int j = 0; j < 4; ++j) {
            int gc = c0 + tx*4 + j;
            float v = acc[i][j] + (bias ? bias[gc] : 0.f);
            if (mat == 0)      qA[(size_t)gr*DOUT + gc] = f2bf(v);
            else if (mat == 1) kA[(size_t)gr*DOUT + gc] = f2bf(v);
            else if (mat == 2) {
                int b = gr >> 11, n = gr & 2047;
                vT[((size_t)b*DOUT + gc)*NN + n] = f2bf(v);
            } else projb[(size_t)gr*DOUT + gc] = f2bf(v);
        }
    }
}

// ---------------- Kernel 3: q2,k2 (bf16), vT (transposed) = h @ W (+bias) ----------------
__global__ __launch_bounds__(256) void k_gemm2(
    const bf16* __restrict__ h,
    const float* __restrict__ q2w, const float* __restrict__ q2b,
    const float* __restrict__ k2w, const float* __restrict__ k2b,
    const float* __restrict__ v2w, const float* __restrict__ v2b,
    bf16* __restrict__ qA, bf16* __restrict__ kA, bf16* __restrict__ vT)
{
    __shared__ float At[64][65];
    __shared__ float Wt[64][65];
    const int rb = blockIdx.x, cb = blockIdx.y;
    const int mat = cb >> 1, c0 = (cb & 1)*64;
    const float* W    = (mat==0)? q2w : (mat==1)? k2w : v2w;
    const float* bias = (mat==0)? q2b : (mat==1)? k2b : v2b;
    const int t = threadIdx.x, ty = t >> 4, tx = t & 15, row0 = rb*64;
    float acc[4][4] = {};
    for (int kc = 0; kc < 2; ++kc) {
        __syncthreads();
        for (int e = t; e < 64*64; e += 256) {
            int r = e >> 6, c = e & 63;
            At[r][c] = bf2f(h[(size_t)(row0+r)*DOUT + kc*64 + c]);
            Wt[r][c] = W[(kc*64+r)*DOUT + c0 + c];
        }
        __syncthreads();
        #pragma unroll 8
        for (int k = 0; k < 64; ++k) {
            float av[4], bv[4];
            #pragma unroll
            for (int i = 0; i < 4; ++i) av[i] = At[ty*4+i][k];
            #pragma unroll
            for (int j = 0; j < 4; ++j) bv[j] = Wt[k][tx*4+j];
            #pragma unroll
            for (int i = 0; i < 4; ++i)
                #pragma unroll
                for (int j = 0; j < 4; ++j)
                    acc[i][j] = fmaf(av[i], bv[j], acc[i][j]);
        }
    }
    #pragma unroll
    for (int i = 0; i < 4; ++i) {
        int gr = row0 + ty*4 + i;
        #pragma unroll
        for (int j = 0; j < 4; ++j) {
            int gc = c0 + tx*4 + j;
            float v = acc[i][j] + bias[gc];
            if (mat == 0)      qA[(size_t)gr*DOUT + gc] = f2bf(v);
            else if (mat == 1) kA[(size_t)gr*DOUT + gc] = f2bf(v);
            else {
                int b = gr >> 11, n = gr & 2047;
                vT[((size_t)b*DOUT + gc)*NN + n] = f2bf(v);
            }
        }
    }
}

// ---------------- MFMA attention v5: 128 queries/block share K/V stream; NO atomics ----------------
// r11 post-mortem: the 8-wave K/V-sharing cut fabric reads 8x (FETCH 17MB), but the
// fp32 atomicAdd merge added 131MB of HBM write traffic + serialization (one 40ms
// dispatch). v5 keeps the sharing, replaces the merge:
//   MODE 0 (gat1, D=32): KS=1, each wave owns its 16 queries end-to-end ->
//          divide/ReLU/write h directly. No merge at all.
//   MODE 1 (gat2, D=128): KS=4 key split; each block stores its partial numerator
//          (bf16) + partial l (fp32) with plain coalesced stores; k_merge2 sums.
// Inner pipeline identical to r9/r10-proven code (S^T operand swap, bpermute
// P-gather, no-max softmax, register double-buffered K/V prefetch).
template<int D, int MODE, int KS>
__global__ __launch_bounds__(512, 2) void k_attn_v5(
    const bf16* __restrict__ qA, const bf16* __restrict__ kA, const bf16* __restrict__ vT,
    bf16* __restrict__ hout, bf16* __restrict__ numerb, float* __restrict__ lpart)
{
    constexpr int NKS = D / 32;     // 32-dim k-steps in S^T
    constexpr int NMT = D / 16;     // 16-dim m-tiles of O^T
    constexpr int ITERS = NN / (32 * KS);   // 32 keys per iteration

    const float scale = (D == 32) ? 0.17677669529663687f : 0.08838834764831843f;
    const int qg = blockIdx.x;                 // 16 groups of 128 queries
    const int bh = blockIdx.y;
    const int ksb = (MODE == 1) ? blockIdx.z : 0;
    const int b  = (MODE == 0) ? (bh >> 2) : bh;
    const int hd = (MODE == 0) ? (bh & 3) : 0;
    const int wave = threadIdx.x >> 6, lane = threadIdx.x & 63;
    const int n16 = lane & 15, q4 = lane >> 4;
    const int q0 = qg*128 + wave*16;           // this wave's 16-query tile

    const short* qbase = (const short*)qA + ((size_t)b*NN)*DOUT + hd*32;
    const short* kbase = (const short*)kA + ((size_t)b*NN)*DOUT + hd*32;
    const short* vbase = (const short*)vT + ((size_t)b*DOUT + hd*32)*NN;

    // Q B-fragments (B[k=dim=q4*8+j][n=query=n16]) — held in regs for all iters
    short8 qf[NKS];
    #pragma unroll
    for (int kq = 0; kq < NKS; ++kq)
        qf[kq] = *(const short8*)(qbase + (size_t)(q0 + n16)*DOUT + kq*32 + q4*8);

    f32x4 acc[NMT];
    #pragma unroll
    for (int mt = 0; mt < NMT; ++mt) acc[mt] = f32x4{0.f, 0.f, 0.f, 0.f};
    float l_lane = 0.f;   // all in-loop exp values belong to query n16

    // bpermute source lanes for the P gather (r9-verified)
    const int srcA = n16 + ((q4 & 1) * 2) * 16;
    const int srcB = srcA + 16;
    const bool selhi = (q4 >= 2);

    const int ktb = ksb * ITERS;    // this block's first 32-key chunk

    short8 kfr[2][2*NKS];           // K frags double-buffered
    short8 vfr[2][NMT];             // V frags double-buffered

    auto loadK = [&](int it, int buf) {
        const short* krow = kbase + (size_t)((ktb + it)*32)*DOUT;
        #pragma unroll
        for (int mt = 0; mt < 2; ++mt)
            #pragma unroll
            for (int kq = 0; kq < NKS; ++kq)
                kfr[buf][mt*NKS + kq] =
                    *(const short8*)(krow + (size_t)(mt*16 + n16)*DOUT + kq*32 + q4*8);
    };
    auto loadV = [&](int it, int buf) {
        const short* vcol = vbase + (size_t)(ktb + it)*32 + q4*8;
        #pragma unroll
        for (int mt = 0; mt < NMT; ++mt)
            vfr[buf][mt] = *(const short8*)(vcol + (size_t)(mt*16 + n16)*NN);
    };

    loadK(0, 0);
    loadV(0, 0);

    for (int it = 0; it < ITERS; ++it) {
        const int cur = it & 1, nxt = cur ^ 1;
        if (it + 1 < ITERS) { loadK(it + 1, nxt); loadV(it + 1, nxt); }
        // ---- S^T: 2 m-tiles of 16 keys. A=K, B=Q (swap) -> col=query, row=key.
        f32x4 sc[2];
        #pragma unroll
        for (int mt = 0; mt < 2; ++mt) {
            f32x4 c = f32x4{0.f, 0.f, 0.f, 0.f};
            #pragma unroll
            for (int kq = 0; kq < NKS; ++kq)
                c = __builtin_amdgcn_mfma_f32_16x16x32_bf16(kfr[cur][mt*NKS + kq], qf[kq], c, 0, 0, 0);
            #pragma unroll
            for (int r = 0; r < 4; ++r) {
                float p = __expf(c[r] * scale);   // no-max softmax (|s|<~4, r8-verified)
                c[r] = p;
                l_lane += p;
            }
            sc[mt] = c;
        }
        // ---- pack P^T tiles to bf16 pairs
        unsigned w0v[2], w1v[2];
        #pragma unroll
        for (int mt = 0; mt < 2; ++mt) {
            w0v[mt] = bfbits(sc[mt][0]) | (bfbits(sc[mt][1]) << 16);
            w1v[mt] = bfbits(sc[mt][2]) | (bfbits(sc[mt][3]) << 16);
        }
        // ---- gather P B-fragment via bpermute (r9-verified mapping)
        int4v pw;
        { unsigned a = __shfl(w0v[0], srcA), bx = __shfl(w0v[1], srcA);
          pw.x = selhi ? (int)bx : (int)a; }
        { unsigned a = __shfl(w1v[0], srcA), bx = __shfl(w1v[1], srcA);
          pw.y = selhi ? (int)bx : (int)a; }
        { unsigned a = __shfl(w0v[0], srcB), bx = __shfl(w0v[1], srcB);
          pw.z = selhi ? (int)bx : (int)a; }
        { unsigned a = __shfl(w1v[0], srcB), bx = __shfl(w1v[1], srcB);
          pw.w = selhi ? (int)bx : (int)a; }
        short8 pf = __builtin_bit_cast(short8, pw);
        // ---- PV: O^T += V^T * P^T (one 32-key k-step)
        #pragma unroll
        for (int mt = 0; mt < NMT; ++mt)
            acc[mt] = __builtin_amdgcn_mfma_f32_16x16x32_bf16(vfr[cur][mt], pf, acc[mt], 0, 0, 0);
    }

    // l reduction over the 4 q4-groups: every lane ends with l for query n16
    l_lane += __shfl_xor(l_lane, 16);
    l_lane += __shfl_xor(l_lane, 32);

    if (MODE == 0) {
        // complete result (KS=1): divide, ReLU, write h directly
        float di = 1.f / l_lane;
        size_t rb = ((size_t)b*NN + q0 + n16)*DOUT + hd*32;
        #pragma unroll
        for (int mt = 0; mt < NMT; ++mt) {
            unsigned lo = bfbits(fmaxf(acc[mt][0]*di, 0.f)) | (bfbits(fmaxf(acc[mt][1]*di, 0.f)) << 16);
            unsigned hi = bfbits(fmaxf(acc[mt][2]*di, 0.f)) | (bfbits(fmaxf(acc[mt][3]*di, 0.f)) << 16);
            uint2 w2{lo, hi};
            *(uint2*)&hout[rb + mt*16 + q4*4] = w2;
        }
    } else {
        // partial: plain stores into slot ksb (no atomics)
        const int row = b*NN + q0 + n16;
        if (q4 == 0) lpart[ksb*NB*NN + row] = l_lane;
        size_t basep = ((size_t)ksb*NB*NN + row)*DOUT;
        #pragma unroll
        for (int mt = 0; mt < NMT; ++mt) {
            unsigned lo = bfbits(acc[mt][0]) | (bfbits(acc[mt][1]) << 16);
            unsigned hi = bfbits(acc[mt][2]) | (bfbits(acc[mt][3]) << 16);
            uint2 w2{lo, hi};
            *(uint2*)&numerb[basep + mt*16 + q4*4] = w2;
        }
    }
}

// ---------------- merge2: sum 4 partials + proj residual + LayerNorm -> fp32 out ----------------
__global__ __launch_bounds__(256) void k_merge2(
    const bf16* __restrict__ numerb, const float* __restrict__ lpart,
    const bf16* __restrict__ projb,
    const float* __restrict__ lng, const float* __restrict__ lnb,
    float* __restrict__ out)
{
    const int wave = threadIdx.x >> 6, lane = threadIdx.x & 63;
    const int row = blockIdx.x * 4 + wave;      // 8192 rows
    float l = 0.f;
    #pragma unroll
    for (int s = 0; s < 4; ++s) l += lpart[s*NB*NN + row];
    float di = 1.f / l;
    float ylo = 0.f, yhi = 0.f;
    #pragma unroll
    for (int s = 0; s < 4; ++s) {
        size_t bp = ((size_t)s*NB*NN + row)*DOUT;
        ylo += bf2f(numerb[bp + lane]);
        yhi += bf2f(numerb[bp + lane + 64]);
    }
    size_t base = (size_t)row * DOUT;
    ylo = ylo*di + bf2f(projb[base + lane]);
    yhi = yhi*di + bf2f(projb[base + lane + 64]);
    float ssum = ylo + yhi;
    #pragma unroll
    for (int off = 32; off >= 1; off >>= 1) ssum += __shfl_xor(ssum, off);
    float mu = ssum * (1.f/128.f);
    float dlo = ylo - mu, dhi = yhi - mu;
    float vs = dlo*dlo + dhi*dhi;
    #pragma unroll
    for (int off = 32; off >= 1; off >>= 1) vs += __shfl_xor(vs, off);
    float rs = rsqrtf(vs * (1.f/128.f) + 1e-3f);
    float o0 = dlo*rs*lng[lane]    + lnb[lane];
    float o1 = dhi*rs*lng[lane+64] + lnb[lane+64];
    if (!(o0 == o0)) o0 = 12345.0f;  // NaN sentinel (never hit on a passing run)
    if (!(o1 == o1)) o1 = 12345.0f;
    out[base + lane]      = o0;
    out[base + lane + 64] = o1;
}

extern "C" void kernel_launch(void* const* d_in, const int* in_sizes, int n_in,
                              void* d_out, int out_size, void* d_ws, size_t ws_size,
                              hipStream_t stream)
{
    const float* x   = (const float*)d_in[0];
    // d_in[1] = emb is dead: adj = sigmoid(l2norm(emb)@l2norm(emb)^T) in [0.27,1],
    // diag forced 1 -> adj==0 never true -> dense attention.
    const float* q1w = (const float*)d_in[2];
    const float* q1b = (const float*)d_in[3];
    const float* k1w = (const float*)d_in[4];
    const float* k1b = (const float*)d_in[5];
    const float* v1w = (const float*)d_in[6];
    const float* v1b = (const float*)d_in[7];
    const float* q2w = (const float*)d_in[8];
    const float* q2b = (const float*)d_in[9];
    const float* k2w = (const float*)d_in[10];
    const float* k2b = (const float*)d_in[11];
    const float* v2w = (const float*)d_in[12];
    const float* v2b = (const float*)d_in[13];
    const float* pw  = (const float*)d_in[14];
    const float* lng = (const float*)d_in[15];
    const float* lnb = (const float*)d_in[16];

    // Workspace: 18.2 MB.
    char* wsb = (char*)d_ws;
    bf16*  qA     = (bf16*)(wsb + 0x000000);   // 2 MB
    bf16*  kA     = (bf16*)(wsb + 0x200000);   // 2 MB
    bf16*  vT     = (bf16*)(wsb + 0x400000);   // 2 MB  [b][128][2048]
    bf16*  projb  = (bf16*)(wsb + 0x600000);   // 2 MB
    bf16*  h      = (bf16*)(wsb + 0x800000);   // 2 MB
    bf16*  numerb = (bf16*)(wsb + 0xA00000);   // 8 MB  (4 KS slots x 2 MB)
    float* lpart  = (float*)(wsb + 0x1200000); // 128 KB

    k_gemm1<<<dim3(128, 8), 256, 0, stream>>>(x, q1w, q1b, k1w, k1b, v1w, v1b, pw,
                                              qA, kA, vT, projb);
    // attn1: D=32, KS=1, grid (16 qg, 16 bh) = 256 blocks x 8 waves; direct h write
    k_attn_v5<32, 0, 1><<<dim3(16, 16), 512, 0, stream>>>(
        qA, kA, vT, h, nullptr, nullptr);
    k_gemm2<<<dim3(128, 6), 256, 0, stream>>>(h, q2w, q2b, k2w, k2b, v2w, v2b,
                                              qA, kA, vT);
    // attn2: D=128, KS=4, grid (16 qg, 4 b, 4 ks) = 256 blocks x 8 waves; partial stores
    k_attn_v5<128, 1, 4><<<dim3(16, 4, 4), 512, 0, stream>>>(
        qA, kA, vT, nullptr, numerb, lpart);
    k_merge2<<<2048, 256, 0, stream>>>(numerb, lpart, projb, lng, lnb, (float*)d_out);
}

// Round 13
// 400.524 us; speedup vs baseline: 1.8667x; 1.8667x over previous
//
#include <hip/hip_runtime.h>
#include <hip/hip_bf16.h>

#define NB 4
#define NN 2048
#define FIN 64
#define DOUT 128

typedef __hip_bfloat16 bf16;
typedef __attribute__((ext_vector_type(8))) short short8;
typedef __attribute__((ext_vector_type(4))) float f32x4;
typedef __attribute__((ext_vector_type(4))) int int4v;

static __device__ __forceinline__ float bf2f(bf16 v) { return __bfloat162float(v); }
static __device__ __forceinline__ bf16  f2bf(float v) { return __float2bfloat16(v); }
static __device__ __forceinline__ unsigned bfbits(float v) {
    bf16 h = __float2bfloat16(v);
    return (unsigned)*reinterpret_cast<unsigned short*>(&h);
}

// ---------------- Kernel 1: q1,k1 (bf16), vT (bf16 transposed), proj (bf16) ----------------
__global__ __launch_bounds__(256) void k_gemm1(
    const float* __restrict__ x,
    const float* __restrict__ q1w, const float* __restrict__ q1b,
    const float* __restrict__ k1w, const float* __restrict__ k1b,
    const float* __restrict__ v1w, const float* __restrict__ v1b,
    const float* __restrict__ pw,
    bf16* __restrict__ qA, bf16* __restrict__ kA, bf16* __restrict__ vT,
    bf16* __restrict__ projb)
{
    __shared__ float At[64][65];
    __shared__ float Wt[64][65];
    const int rb = blockIdx.x;
    const int cb = blockIdx.y;
    const int mat = cb >> 1;
    const int c0 = (cb & 1) * 64;
    const float* W    = (mat==0)? q1w : (mat==1)? k1w : (mat==2)? v1w : pw;
    const float* bias = (mat==0)? q1b : (mat==1)? k1b : (mat==2)? v1b : nullptr;
    const int t = threadIdx.x;
    const int row0 = rb * 64;
    for (int e = t; e < 64*64; e += 256) {
        int r = e >> 6, c = e & 63;
        At[r][c] = x[(size_t)(row0 + r)*FIN + c];
        Wt[r][c] = W[r*DOUT + c0 + c];
    }
    __syncthreads();
    const int ty = t >> 4, tx = t & 15;
    float acc[4][4] = {};
    #pragma unroll 8
    for (int k = 0; k < 64; ++k) {
        float av[4], bv[4];
        #pragma unroll
        for (int i = 0; i < 4; ++i) av[i] = At[ty*4+i][k];
        #pragma unroll
        for (int j = 0; j < 4; ++j) bv[j] = Wt[k][tx*4+j];
        #pragma unroll
        for (int i = 0; i < 4; ++i)
            #pragma unroll
            for (int j = 0; j < 4; ++j)
                acc[i][j] = fmaf(av[i], bv[j], acc[i][j]);
    }
    #pragma unroll
    for (int i = 0; i < 4; ++i) {
        int gr = row0 + ty*4 + i;
        #pragma unroll
        for (int j = 0; j < 4; ++j) {
            int gc = c0 + tx*4 + j;
            float v = acc[i][j] + (bias ? bias[gc] : 0.f);
            if (mat == 0)      qA[(size_t)gr*DOUT + gc] = f2bf(v);
            else if (mat == 1) kA[(size_t)gr*DOUT + gc] = f2bf(v);
            else if (mat == 2) {
                int b = gr >> 11, n = gr & 2047;
                vT[((size_t)b*DOUT + gc)*NN + n] = f2bf(v);
            } else projb[(size_t)gr*DOUT + gc] = f2bf(v);
        }
    }
}

// ---------------- Kernel 3: q2,k2 (bf16), vT (transposed) = h @ W (+bias) ----------------
__global__ __launch_bounds__(256) void k_gemm2(
    const bf16* __restrict__ h,
    const float* __restrict__ q2w, const float* __restrict__ q2b,
    const float* __restrict__ k2w, const float* __restrict__ k2b,
    const float* __restrict__ v2w, const float* __restrict__ v2b,
    bf16* __restrict__ qA, bf16* __restrict__ kA, bf16* __restrict__ vT)
{
    __shared__ float At[64][65];
    __shared__ float Wt[64][65];
    const int rb = blockIdx.x, cb = blockIdx.y;
    const int mat = cb >> 1, c0 = (cb & 1)*64;
    const float* W    = (mat==0)? q2w : (mat==1)? k2w : v2w;
    const float* bias = (mat==0)? q2b : (mat==1)? k2b : v2b;
    const int t = threadIdx.x, ty = t >> 4, tx = t & 15, row0 = rb*64;
    float acc[4][4] = {};
    for (int kc = 0; kc < 2; ++kc) {
        __syncthreads();
        for (int e = t; e < 64*64; e += 256) {
            int r = e >> 6, c = e & 63;
            At[r][c] = bf2f(h[(size_t)(row0+r)*DOUT + kc*64 + c]);
            Wt[r][c] = W[(kc*64+r)*DOUT + c0 + c];
        }
        __syncthreads();
        #pragma unroll 8
        for (int k = 0; k < 64; ++k) {
            float av[4], bv[4];
            #pragma unroll
            for (int i = 0; i < 4; ++i) av[i] = At[ty*4+i][k];
            #pragma unroll
            for (int j = 0; j < 4; ++j) bv[j] = Wt[k][tx*4+j];
            #pragma unroll
            for (int i = 0; i < 4; ++i)
                #pragma unroll
                for (int j = 0; j < 4; ++j)
                    acc[i][j] = fmaf(av[i], bv[j], acc[i][j]);
        }
    }
    #pragma unroll
    for (int i = 0; i < 4; ++i) {
        int gr = row0 + ty*4 + i;
        #pragma unroll
        for (int j = 0; j < 4; ++j) {
            int gc = c0 + tx*4 + j;
            float v = acc[i][j] + bias[gc];
            if (mat == 0)      qA[(size_t)gr*DOUT + gc] = f2bf(v);
            else if (mat == 1) kA[(size_t)gr*DOUT + gc] = f2bf(v);
            else {
                int b = gr >> 11, n = gr & 2047;
                vT[((size_t)b*DOUT + gc)*NN + n] = f2bf(v);
            }
        }
    }
}

// ---------------- MFMA attention v5b: v5 with the key loop UNROLLED ----------------
// r12 post-mortem: dropping '#pragma unroll' made cur=it&1 dynamic -> the
// double-buffer fragment arrays were no longer register-resident (VGPR=64) and the
// compiler emitted massive VALU emulation (VALUBusy 80.7%, attn1 609us). Restoring
// the unroll makes all indices constant -> r10-class code, now with the v5
// architecture: 8 waves/block share ONE K/V stream (8x less L2/L3 read traffic),
// no atomics, no in-loop LDS/barriers.
//   MODE 0 (gat1, D=32): KS=1, each wave owns 16 queries end-to-end -> direct h write.
//   MODE 1 (gat2, D=128): KS=4 key split; bf16 partial numerator + fp32 partial l
//          stored with plain coalesced stores; k_merge2 sums.
template<int D, int MODE, int KS>
__global__ __launch_bounds__(512, 2) void k_attn_v5(
    const bf16* __restrict__ qA, const bf16* __restrict__ kA, const bf16* __restrict__ vT,
    bf16* __restrict__ hout, bf16* __restrict__ numerb, float* __restrict__ lpart)
{
    constexpr int NKS = D / 32;     // 32-dim k-steps in S^T
    constexpr int NMT = D / 16;     // 16-dim m-tiles of O^T
    constexpr int ITERS = NN / (32 * KS);   // 32 keys per iteration

    const float scale = (D == 32) ? 0.17677669529663687f : 0.08838834764831843f;
    const int qg = blockIdx.x;                 // 16 groups of 128 queries
    const int bh = blockIdx.y;
    const int ksb = (MODE == 1) ? blockIdx.z : 0;
    const int b  = (MODE == 0) ? (bh >> 2) : bh;
    const int hd = (MODE == 0) ? (bh & 3) : 0;
    const int wave = threadIdx.x >> 6, lane = threadIdx.x & 63;
    const int n16 = lane & 15, q4 = lane >> 4;
    const int q0 = qg*128 + wave*16;           // this wave's 16-query tile

    const short* qbase = (const short*)qA + ((size_t)b*NN)*DOUT + hd*32;
    const short* kbase = (const short*)kA + ((size_t)b*NN)*DOUT + hd*32;
    const short* vbase = (const short*)vT + ((size_t)b*DOUT + hd*32)*NN;

    // Q B-fragments (B[k=dim=q4*8+j][n=query=n16]) — held in regs for all iters
    short8 qf[NKS];
    #pragma unroll
    for (int kq = 0; kq < NKS; ++kq)
        qf[kq] = *(const short8*)(qbase + (size_t)(q0 + n16)*DOUT + kq*32 + q4*8);

    f32x4 acc[NMT];
    #pragma unroll
    for (int mt = 0; mt < NMT; ++mt) acc[mt] = f32x4{0.f, 0.f, 0.f, 0.f};
    float l_lane = 0.f;   // all in-loop exp values belong to query n16

    // bpermute source lanes for the P gather (r9-verified)
    const int srcA = n16 + ((q4 & 1) * 2) * 16;
    const int srcB = srcA + 16;
    const bool selhi = (q4 >= 2);

    const int ktb = ksb * ITERS;    // this block's first 32-key chunk

    short8 kfr[2][2*NKS];           // K frags double-buffered (constant-indexed!)
    short8 vfr[2][NMT];             // V frags double-buffered

    auto loadK = [&](int it, int buf) {
        const short* krow = kbase + (size_t)((ktb + it)*32)*DOUT;
        #pragma unroll
        for (int mt = 0; mt < 2; ++mt)
            #pragma unroll
            for (int kq = 0; kq < NKS; ++kq)
                kfr[buf][mt*NKS + kq] =
                    *(const short8*)(krow + (size_t)(mt*16 + n16)*DOUT + kq*32 + q4*8);
    };
    auto loadV = [&](int it, int buf) {
        const short* vcol = vbase + (size_t)(ktb + it)*32 + q4*8;
        #pragma unroll
        for (int mt = 0; mt < NMT; ++mt)
            vfr[buf][mt] = *(const short8*)(vcol + (size_t)(mt*16 + n16)*NN);
    };

    loadK(0, 0);
    loadV(0, 0);

    #pragma unroll                   // <- THE r12 regression: must be unrolled so
    for (int it = 0; it < ITERS; ++it) {  // cur/nxt are constants and frags stay in VGPRs
        const int cur = it & 1, nxt = cur ^ 1;
        if (it + 1 < ITERS) { loadK(it + 1, nxt); loadV(it + 1, nxt); }
        // ---- S^T: 2 m-tiles of 16 keys. A=K, B=Q (swap) -> col=query, row=key.
        f32x4 sc[2];
        #pragma unroll
        for (int mt = 0; mt < 2; ++mt) {
            f32x4 c = f32x4{0.f, 0.f, 0.f, 0.f};
            #pragma unroll
            for (int kq = 0; kq < NKS; ++kq)
                c = __builtin_amdgcn_mfma_f32_16x16x32_bf16(kfr[cur][mt*NKS + kq], qf[kq], c, 0, 0, 0);
            #pragma unroll
            for (int r = 0; r < 4; ++r) {
                float p = __expf(c[r] * scale);   // no-max softmax (|s|<~4, r8-verified)
                c[r] = p;
                l_lane += p;
            }
            sc[mt] = c;
        }
        // ---- pack P^T tiles to bf16 pairs
        unsigned w0v[2], w1v[2];
        #pragma unroll
        for (int mt = 0; mt < 2; ++mt) {
            w0v[mt] = bfbits(sc[mt][0]) | (bfbits(sc[mt][1]) << 16);
            w1v[mt] = bfbits(sc[mt][2]) | (bfbits(sc[mt][3]) << 16);
        }
        // ---- gather P B-fragment via bpermute (r9-verified mapping)
        int4v pw;
        { unsigned a = __shfl(w0v[0], srcA), bx = __shfl(w0v[1], srcA);
          pw.x = selhi ? (int)bx : (int)a; }
        { unsigned a = __shfl(w1v[0], srcA), bx = __shfl(w1v[1], srcA);
          pw.y = selhi ? (int)bx : (int)a; }
        { unsigned a = __shfl(w0v[0], srcB), bx = __shfl(w0v[1], srcB);
          pw.z = selhi ? (int)bx : (int)a; }
        { unsigned a = __shfl(w1v[0], srcB), bx = __shfl(w1v[1], srcB);
          pw.w = selhi ? (int)bx : (int)a; }
        short8 pf = __builtin_bit_cast(short8, pw);
        // ---- PV: O^T += V^T * P^T (one 32-key k-step)
        #pragma unroll
        for (int mt = 0; mt < NMT; ++mt)
            acc[mt] = __builtin_amdgcn_mfma_f32_16x16x32_bf16(vfr[cur][mt], pf, acc[mt], 0, 0, 0);
    }

    // l reduction over the 4 q4-groups: every lane ends with l for query n16
    l_lane += __shfl_xor(l_lane, 16);
    l_lane += __shfl_xor(l_lane, 32);

    if (MODE == 0) {
        // complete result (KS=1): divide, ReLU, write h directly
        float di = 1.f / l_lane;
        size_t rb = ((size_t)b*NN + q0 + n16)*DOUT + hd*32;
        #pragma unroll
        for (int mt = 0; mt < NMT; ++mt) {
            unsigned lo = bfbits(fmaxf(acc[mt][0]*di, 0.f)) | (bfbits(fmaxf(acc[mt][1]*di, 0.f)) << 16);
            unsigned hi = bfbits(fmaxf(acc[mt][2]*di, 0.f)) | (bfbits(fmaxf(acc[mt][3]*di, 0.f)) << 16);
            uint2 w2{lo, hi};
            *(uint2*)&hout[rb + mt*16 + q4*4] = w2;
        }
    } else {
        // partial: plain stores into slot ksb (no atomics)
        const int row = b*NN + q0 + n16;
        if (q4 == 0) lpart[ksb*NB*NN + row] = l_lane;
        size_t basep = ((size_t)ksb*NB*NN + row)*DOUT;
        #pragma unroll
        for (int mt = 0; mt < NMT; ++mt) {
            unsigned lo = bfbits(acc[mt][0]) | (bfbits(acc[mt][1]) << 16);
            unsigned hi = bfbits(acc[mt][2]) | (bfbits(acc[mt][3]) << 16);
            uint2 w2{lo, hi};
            *(uint2*)&numerb[basep + mt*16 + q4*4] = w2;
        }
    }
}

// ---------------- merge2: sum 4 partials + proj residual + LayerNorm -> fp32 out ----------------
__global__ __launch_bounds__(256) void k_merge2(
    const bf16* __restrict__ numerb, const float* __restrict__ lpart,
    const bf16* __restrict__ projb,
    const float* __restrict__ lng, const float* __restrict__ lnb,
    float* __restrict__ out)
{
    const int wave = threadIdx.x >> 6, lane = threadIdx.x & 63;
    const int row = blockIdx.x * 4 + wave;      // 8192 rows
    float l = 0.f;
    #pragma unroll
    for (int s = 0; s < 4; ++s) l += lpart[s*NB*NN + row];
    float di = 1.f / l;
    float ylo = 0.f, yhi = 0.f;
    #pragma unroll
    for (int s = 0; s < 4; ++s) {
        size_t bp = ((size_t)s*NB*NN + row)*DOUT;
        ylo += bf2f(numerb[bp + lane]);
        yhi += bf2f(numerb[bp + lane + 64]);
    }
    size_t base = (size_t)row * DOUT;
    ylo = ylo*di + bf2f(projb[base + lane]);
    yhi = yhi*di + bf2f(projb[base + lane + 64]);
    float ssum = ylo + yhi;
    #pragma unroll
    for (int off = 32; off >= 1; off >>= 1) ssum += __shfl_xor(ssum, off);
    float mu = ssum * (1.f/128.f);
    float dlo = ylo - mu, dhi = yhi - mu;
    float vs = dlo*dlo + dhi*dhi;
    #pragma unroll
    for (int off = 32; off >= 1; off >>= 1) vs += __shfl_xor(vs, off);
    float rs = rsqrtf(vs * (1.f/128.f) + 1e-3f);
    float o0 = dlo*rs*lng[lane]    + lnb[lane];
    float o1 = dhi*rs*lng[lane+64] + lnb[lane+64];
    if (!(o0 == o0)) o0 = 12345.0f;  // NaN sentinel (never hit on a passing run)
    if (!(o1 == o1)) o1 = 12345.0f;
    out[base + lane]      = o0;
    out[base + lane + 64] = o1;
}

extern "C" void kernel_launch(void* const* d_in, const int* in_sizes, int n_in,
                              void* d_out, int out_size, void* d_ws, size_t ws_size,
                              hipStream_t stream)
{
    const float* x   = (const float*)d_in[0];
    // d_in[1] = emb is dead: adj = sigmoid(l2norm(emb)@l2norm(emb)^T) in [0.27,1],
    // diag forced 1 -> adj==0 never true -> dense attention.
    const float* q1w = (const float*)d_in[2];
    const float* q1b = (const float*)d_in[3];
    const float* k1w = (const float*)d_in[4];
    const float* k1b = (const float*)d_in[5];
    const float* v1w = (const float*)d_in[6];
    const float* v1b = (const float*)d_in[7];
    const float* q2w = (const float*)d_in[8];
    const float* q2b = (const float*)d_in[9];
    const float* k2w = (const float*)d_in[10];
    const float* k2b = (const float*)d_in[11];
    const float* v2w = (const float*)d_in[12];
    const float* v2b = (const float*)d_in[13];
    const float* pw  = (const float*)d_in[14];
    const float* lng = (const float*)d_in[15];
    const float* lnb = (const float*)d_in[16];

    // Workspace: 18.2 MB.
    char* wsb = (char*)d_ws;
    bf16*  qA     = (bf16*)(wsb + 0x000000);   // 2 MB
    bf16*  kA     = (bf16*)(wsb + 0x200000);   // 2 MB
    bf16*  vT     = (bf16*)(wsb + 0x400000);   // 2 MB  [b][128][2048]
    bf16*  projb  = (bf16*)(wsb + 0x600000);   // 2 MB
    bf16*  h      = (bf16*)(wsb + 0x800000);   // 2 MB
    bf16*  numerb = (bf16*)(wsb + 0xA00000);   // 8 MB  (4 KS slots x 2 MB)
    float* lpart  = (float*)(wsb + 0x1200000); // 128 KB

    k_gemm1<<<dim3(128, 8), 256, 0, stream>>>(x, q1w, q1b, k1w, k1b, v1w, v1b, pw,
                                              qA, kA, vT, projb);
    // attn1: D=32, KS=1, grid (16 qg, 16 bh) = 256 blocks x 8 waves; direct h write
    k_attn_v5<32, 0, 1><<<dim3(16, 16), 512, 0, stream>>>(
        qA, kA, vT, h, nullptr, nullptr);
    k_gemm2<<<dim3(128, 6), 256, 0, stream>>>(h, q2w, q2b, k2w, k2b, v2w, v2b,
                                              qA, kA, vT);
    // attn2: D=128, KS=4, grid (16 qg, 4 b, 4 ks) = 256 blocks x 8 waves; partial stores
    k_attn_v5<128, 1, 4><<<dim3(16, 4, 4), 512, 0, stream>>>(
        qA, kA, vT, nullptr, numerb, lpart);
    k_merge2<<<2048, 256, 0, stream>>>(numerb, lpart, projb, lng, lnb, (float*)d_out);
}

// Round 14
// 250.948 us; speedup vs baseline: 2.9793x; 1.5960x over previous
//
#include <hip/hip_runtime.h>
#include <hip/hip_bf16.h>

#define NB 4
#define NN 2048
#define FIN 64
#define DOUT 128

typedef __hip_bfloat16 bf16;
typedef __attribute__((ext_vector_type(8))) short short8;
typedef __attribute__((ext_vector_type(4))) float f32x4;
typedef __attribute__((ext_vector_type(4))) int int4v;

static __device__ __forceinline__ float bf2f(bf16 v) { return __bfloat162float(v); }
static __device__ __forceinline__ bf16  f2bf(float v) { return __float2bfloat16(v); }
static __device__ __forceinline__ unsigned bfbits(float v) {
    bf16 h = __float2bfloat16(v);
    return (unsigned)*reinterpret_cast<unsigned short*>(&h);
}

// ---------------- Kernel 1: q1,k1 (bf16), vT (bf16 transposed), proj (bf16) ----------------
__global__ __launch_bounds__(256) void k_gemm1(
    const float* __restrict__ x,
    const float* __restrict__ q1w, const float* __restrict__ q1b,
    const float* __restrict__ k1w, const float* __restrict__ k1b,
    const float* __restrict__ v1w, const float* __restrict__ v1b,
    const float* __restrict__ pw,
    bf16* __restrict__ qA, bf16* __restrict__ kA, bf16* __restrict__ vT,
    bf16* __restrict__ projb)
{
    __shared__ float At[64][65];
    __shared__ float Wt[64][65];
    const int rb = blockIdx.x;
    const int cb = blockIdx.y;
    const int mat = cb >> 1;
    const int c0 = (cb & 1) * 64;
    const float* W    = (mat==0)? q1w : (mat==1)? k1w : (mat==2)? v1w : pw;
    const float* bias = (mat==0)? q1b : (mat==1)? k1b : (mat==2)? v1b : nullptr;
    const int t = threadIdx.x;
    const int row0 = rb * 64;
    for (int e = t; e < 64*64; e += 256) {
        int r = e >> 6, c = e & 63;
        At[r][c] = x[(size_t)(row0 + r)*FIN + c];
        Wt[r][c] = W[r*DOUT + c0 + c];
    }
    __syncthreads();
    const int ty = t >> 4, tx = t & 15;
    float acc[4][4] = {};
    #pragma unroll 8
    for (int k = 0; k < 64; ++k) {
        float av[4], bv[4];
        #pragma unroll
        for (int i = 0; i < 4; ++i) av[i] = At[ty*4+i][k];
        #pragma unroll
        for (int j = 0; j < 4; ++j) bv[j] = Wt[k][tx*4+j];
        #pragma unroll
        for (int i = 0; i < 4; ++i)
            #pragma unroll
            for (int j = 0; j < 4; ++j)
                acc[i][j] = fmaf(av[i], bv[j], acc[i][j]);
    }
    #pragma unroll
    for (int i = 0; i < 4; ++i) {
        int gr = row0 + ty*4 + i;
        #pragma unroll
        for (int j = 0; j < 4; ++j) {
            int gc = c0 + tx*4 + j;
            float v = acc[i][j] + (bias ? bias[gc] : 0.f);
            if (mat == 0)      qA[(size_t)gr*DOUT + gc] = f2bf(v);
            else if (mat == 1) kA[(size_t)gr*DOUT + gc] = f2bf(v);
            else if (mat == 2) {
                int b = gr >> 11, n = gr & 2047;
                vT[((size_t)b*DOUT + gc)*NN + n] = f2bf(v);
            } else projb[(size_t)gr*DOUT + gc] = f2bf(v);
        }
    }
}

// ---------------- Kernel 3: q2,k2 (bf16), vT (transposed) = h @ W (+bias) ----------------
__global__ __launch_bounds__(256) void k_gemm2(
    const bf16* __restrict__ h,
    const float* __restrict__ q2w, const float* __restrict__ q2b,
    const float* __restrict__ k2w, const float* __restrict__ k2b,
    const float* __restrict__ v2w, const float* __restrict__ v2b,
    bf16* __restrict__ qA, bf16* __restrict__ kA, bf16* __restrict__ vT)
{
    __shared__ float At[64][65];
    __shared__ float Wt[64][65];
    const int rb = blockIdx.x, cb = blockIdx.y;
    const int mat = cb >> 1, c0 = (cb & 1)*64;
    const float* W    = (mat==0)? q2w : (mat==1)? k2w : v2w;
    const float* bias = (mat==0)? q2b : (mat==1)? k2b : v2b;
    const int t = threadIdx.x, ty = t >> 4, tx = t & 15, row0 = rb*64;
    float acc[4][4] = {};
    for (int kc = 0; kc < 2; ++kc) {
        __syncthreads();
        for (int e = t; e < 64*64; e += 256) {
            int r = e >> 6, c = e & 63;
            At[r][c] = bf2f(h[(size_t)(row0+r)*DOUT + kc*64 + c]);
            Wt[r][c] = W[(kc*64+r)*DOUT + c0 + c];
        }
        __syncthreads();
        #pragma unroll 8
        for (int k = 0; k < 64; ++k) {
            float av[4], bv[4];
            #pragma unroll
            for (int i = 0; i < 4; ++i) av[i] = At[ty*4+i][k];
            #pragma unroll
            for (int j = 0; j < 4; ++j) bv[j] = Wt[k][tx*4+j];
            #pragma unroll
            for (int i = 0; i < 4; ++i)
                #pragma unroll
                for (int j = 0; j < 4; ++j)
                    acc[i][j] = fmaf(av[i], bv[j], acc[i][j]);
        }
    }
    #pragma unroll
    for (int i = 0; i < 4; ++i) {
        int gr = row0 + ty*4 + i;
        #pragma unroll
        for (int j = 0; j < 4; ++j) {
            int gc = c0 + tx*4 + j;
            float v = acc[i][j] + bias[gc];
            if (mat == 0)      qA[(size_t)gr*DOUT + gc] = f2bf(v);
            else if (mat == 1) kA[(size_t)gr*DOUT + gc] = f2bf(v);
            else {
                int b = gr >> 11, n = gr & 2047;
                vT[((size_t)b*DOUT + gc)*NN + n] = f2bf(v);
            }
        }
    }
}

// ---------------- MFMA attention v5c: v5 with the key loop unrolled BY 2 ----------------
// r12: no unroll -> cur=it&1 dynamic -> fragment arrays not register-resident ->
//      VALU emulation (VALUBusy 81%, 609us).
// r13: FULL unroll (ITERS=64) -> scheduler hoisted loads across the whole body ->
//      VGPR blowout -> scratch spills (WRITE_SIZE 148MB, FETCH 91MB, ~220us).
// v5c: '#pragma unroll 2' -> within the 2x body it&1 is {0,1} = constant (register-
//      resident buffers, no emulation) while the loop stays a loop (no hoist blowout).
// Architecture unchanged: 8 waves/block share ONE K/V stream (8x read-traffic cut,
// r11-verified FETCH 17MB), no atomics, no in-loop LDS/barriers.
//   MODE 0 (gat1, D=32): KS=1, wave owns 16 queries end-to-end -> direct h write.
//   MODE 1 (gat2, D=128): KS=4; bf16 partial numerator + fp32 partial l; k_merge2 sums.
template<int D, int MODE, int KS>
__global__ __launch_bounds__(512, 2) void k_attn_v5(
    const bf16* __restrict__ qA, const bf16* __restrict__ kA, const bf16* __restrict__ vT,
    bf16* __restrict__ hout, bf16* __restrict__ numerb, float* __restrict__ lpart)
{
    constexpr int NKS = D / 32;     // 32-dim k-steps in S^T
    constexpr int NMT = D / 16;     // 16-dim m-tiles of O^T
    constexpr int ITERS = NN / (32 * KS);   // 32 keys per iteration

    const float scale = (D == 32) ? 0.17677669529663687f : 0.08838834764831843f;
    const int qg = blockIdx.x;                 // 16 groups of 128 queries
    const int bh = blockIdx.y;
    const int ksb = (MODE == 1) ? blockIdx.z : 0;
    const int b  = (MODE == 0) ? (bh >> 2) : bh;
    const int hd = (MODE == 0) ? (bh & 3) : 0;
    const int wave = threadIdx.x >> 6, lane = threadIdx.x & 63;
    const int n16 = lane & 15, q4 = lane >> 4;
    const int q0 = qg*128 + wave*16;           // this wave's 16-query tile

    const short* qbase = (const short*)qA + ((size_t)b*NN)*DOUT + hd*32;
    const short* kbase = (const short*)kA + ((size_t)b*NN)*DOUT + hd*32;
    const short* vbase = (const short*)vT + ((size_t)b*DOUT + hd*32)*NN;

    // Q B-fragments (B[k=dim=q4*8+j][n=query=n16]) — held in regs for all iters
    short8 qf[NKS];
    #pragma unroll
    for (int kq = 0; kq < NKS; ++kq)
        qf[kq] = *(const short8*)(qbase + (size_t)(q0 + n16)*DOUT + kq*32 + q4*8);

    f32x4 acc[NMT];
    #pragma unroll
    for (int mt = 0; mt < NMT; ++mt) acc[mt] = f32x4{0.f, 0.f, 0.f, 0.f};
    float l_lane = 0.f;   // all in-loop exp values belong to query n16

    // bpermute source lanes for the P gather (r9-verified)
    const int srcA = n16 + ((q4 & 1) * 2) * 16;
    const int srcB = srcA + 16;
    const bool selhi = (q4 >= 2);

    const int ktb = ksb * ITERS;    // this block's first 32-key chunk

    short8 kfr[2][2*NKS];           // K frags double-buffered (constant-indexed in 2x body)
    short8 vfr[2][NMT];             // V frags double-buffered

    auto loadK = [&](int it, int buf) {
        const short* krow = kbase + (size_t)((ktb + it)*32)*DOUT;
        #pragma unroll
        for (int mt = 0; mt < 2; ++mt)
            #pragma unroll
            for (int kq = 0; kq < NKS; ++kq)
                kfr[buf][mt*NKS + kq] =
                    *(const short8*)(krow + (size_t)(mt*16 + n16)*DOUT + kq*32 + q4*8);
    };
    auto loadV = [&](int it, int buf) {
        const short* vcol = vbase + (size_t)(ktb + it)*32 + q4*8;
        #pragma unroll
        for (int mt = 0; mt < NMT; ++mt)
            vfr[buf][mt] = *(const short8*)(vcol + (size_t)(mt*16 + n16)*NN);
    };

    loadK(0, 0);
    loadV(0, 0);

    #pragma unroll 2   // 2x body: it&1 constant (regs stay allocated) without the
    for (int it = 0; it < ITERS; ++it) {   // r13 full-unroll load-hoist spill blowout
        const int cur = it & 1, nxt = cur ^ 1;
        if (it + 1 < ITERS) { loadK(it + 1, nxt); loadV(it + 1, nxt); }
        // ---- S^T: 2 m-tiles of 16 keys. A=K, B=Q (swap) -> col=query, row=key.
        f32x4 sc[2];
        #pragma unroll
        for (int mt = 0; mt < 2; ++mt) {
            f32x4 c = f32x4{0.f, 0.f, 0.f, 0.f};
            #pragma unroll
            for (int kq = 0; kq < NKS; ++kq)
                c = __builtin_amdgcn_mfma_f32_16x16x32_bf16(kfr[cur][mt*NKS + kq], qf[kq], c, 0, 0, 0);
            #pragma unroll
            for (int r = 0; r < 4; ++r) {
                float p = __expf(c[r] * scale);   // no-max softmax (|s|<~4, r8-verified)
                c[r] = p;
                l_lane += p;
            }
            sc[mt] = c;
        }
        // ---- pack P^T tiles to bf16 pairs
        unsigned w0v[2], w1v[2];
        #pragma unroll
        for (int mt = 0; mt < 2; ++mt) {
            w0v[mt] = bfbits(sc[mt][0]) | (bfbits(sc[mt][1]) << 16);
            w1v[mt] = bfbits(sc[mt][2]) | (bfbits(sc[mt][3]) << 16);
        }
        // ---- gather P B-fragment via bpermute (r9-verified mapping)
        int4v pw;
        { unsigned a = __shfl(w0v[0], srcA), bx = __shfl(w0v[1], srcA);
          pw.x = selhi ? (int)bx : (int)a; }
        { unsigned a = __shfl(w1v[0], srcA), bx = __shfl(w1v[1], srcA);
          pw.y = selhi ? (int)bx : (int)a; }
        { unsigned a = __shfl(w0v[0], srcB), bx = __shfl(w0v[1], srcB);
          pw.z = selhi ? (int)bx : (int)a; }
        { unsigned a = __shfl(w1v[0], srcB), bx = __shfl(w1v[1], srcB);
          pw.w = selhi ? (int)bx : (int)a; }
        short8 pf = __builtin_bit_cast(short8, pw);
        // ---- PV: O^T += V^T * P^T (one 32-key k-step)
        #pragma unroll
        for (int mt = 0; mt < NMT; ++mt)
            acc[mt] = __builtin_amdgcn_mfma_f32_16x16x32_bf16(vfr[cur][mt], pf, acc[mt], 0, 0, 0);
    }

    // l reduction over the 4 q4-groups: every lane ends with l for query n16
    l_lane += __shfl_xor(l_lane, 16);
    l_lane += __shfl_xor(l_lane, 32);

    if (MODE == 0) {
        // complete result (KS=1): divide, ReLU, write h directly
        float di = 1.f / l_lane;
        size_t rb = ((size_t)b*NN + q0 + n16)*DOUT + hd*32;
        #pragma unroll
        for (int mt = 0; mt < NMT; ++mt) {
            unsigned lo = bfbits(fmaxf(acc[mt][0]*di, 0.f)) | (bfbits(fmaxf(acc[mt][1]*di, 0.f)) << 16);
            unsigned hi = bfbits(fmaxf(acc[mt][2]*di, 0.f)) | (bfbits(fmaxf(acc[mt][3]*di, 0.f)) << 16);
            uint2 w2{lo, hi};
            *(uint2*)&hout[rb + mt*16 + q4*4] = w2;
        }
    } else {
        // partial: plain stores into slot ksb (no atomics)
        const int row = b*NN + q0 + n16;
        if (q4 == 0) lpart[ksb*NB*NN + row] = l_lane;
        size_t basep = ((size_t)ksb*NB*NN + row)*DOUT;
        #pragma unroll
        for (int mt = 0; mt < NMT; ++mt) {
            unsigned lo = bfbits(acc[mt][0]) | (bfbits(acc[mt][1]) << 16);
            unsigned hi = bfbits(acc[mt][2]) | (bfbits(acc[mt][3]) << 16);
            uint2 w2{lo, hi};
            *(uint2*)&numerb[basep + mt*16 + q4*4] = w2;
        }
    }
}

// ---------------- merge2: sum 4 partials + proj residual + LayerNorm -> fp32 out ----------------
__global__ __launch_bounds__(256) void k_merge2(
    const bf16* __restrict__ numerb, const float* __restrict__ lpart,
    const bf16* __restrict__ projb,
    const float* __restrict__ lng, const float* __restrict__ lnb,
    float* __restrict__ out)
{
    const int wave = threadIdx.x >> 6, lane = threadIdx.x & 63;
    const int row = blockIdx.x * 4 + wave;      // 8192 rows
    float l = 0.f;
    #pragma unroll
    for (int s = 0; s < 4; ++s) l += lpart[s*NB*NN + row];
    float di = 1.f / l;
    float ylo = 0.f, yhi = 0.f;
    #pragma unroll
    for (int s = 0; s < 4; ++s) {
        size_t bp = ((size_t)s*NB*NN + row)*DOUT;
        ylo += bf2f(numerb[bp + lane]);
        yhi += bf2f(numerb[bp + lane + 64]);
    }
    size_t base = (size_t)row * DOUT;
    ylo = ylo*di + bf2f(projb[base + lane]);
    yhi = yhi*di + bf2f(projb[base + lane + 64]);
    float ssum = ylo + yhi;
    #pragma unroll
    for (int off = 32; off >= 1; off >>= 1) ssum += __shfl_xor(ssum, off);
    float mu = ssum * (1.f/128.f);
    float dlo = ylo - mu, dhi = yhi - mu;
    float vs = dlo*dlo + dhi*dhi;
    #pragma unroll
    for (int off = 32; off >= 1; off >>= 1) vs += __shfl_xor(vs, off);
    float rs = rsqrtf(vs * (1.f/128.f) + 1e-3f);
    float o0 = dlo*rs*lng[lane]    + lnb[lane];
    float o1 = dhi*rs*lng[lane+64] + lnb[lane+64];
    if (!(o0 == o0)) o0 = 12345.0f;  // NaN sentinel (never hit on a passing run)
    if (!(o1 == o1)) o1 = 12345.0f;
    out[base + lane]      = o0;
    out[base + lane + 64] = o1;
}

extern "C" void kernel_launch(void* const* d_in, const int* in_sizes, int n_in,
                              void* d_out, int out_size, void* d_ws, size_t ws_size,
                              hipStream_t stream)
{
    const float* x   = (const float*)d_in[0];
    // d_in[1] = emb is dead: adj = sigmoid(l2norm(emb)@l2norm(emb)^T) in [0.27,1],
    // diag forced 1 -> adj==0 never true -> dense attention.
    const float* q1w = (const float*)d_in[2];
    const float* q1b = (const float*)d_in[3];
    const float* k1w = (const float*)d_in[4];
    const float* k1b = (const float*)d_in[5];
    const float* v1w = (const float*)d_in[6];
    const float* v1b = (const float*)d_in[7];
    const float* q2w = (const float*)d_in[8];
    const float* q2b = (const float*)d_in[9];
    const float* k2w = (const float*)d_in[10];
    const float* k2b = (const float*)d_in[11];
    const float* v2w = (const float*)d_in[12];
    const float* v2b = (const float*)d_in[13];
    const float* pw  = (const float*)d_in[14];
    const float* lng = (const float*)d_in[15];
    const float* lnb = (const float*)d_in[16];

    // Workspace: 18.2 MB.
    char* wsb = (char*)d_ws;
    bf16*  qA     = (bf16*)(wsb + 0x000000);   // 2 MB
    bf16*  kA     = (bf16*)(wsb + 0x200000);   // 2 MB
    bf16*  vT     = (bf16*)(wsb + 0x400000);   // 2 MB  [b][128][2048]
    bf16*  projb  = (bf16*)(wsb + 0x600000);   // 2 MB
    bf16*  h      = (bf16*)(wsb + 0x800000);   // 2 MB
    bf16*  numerb = (bf16*)(wsb + 0xA00000);   // 8 MB  (4 KS slots x 2 MB)
    float* lpart  = (float*)(wsb + 0x1200000); // 128 KB

    k_gemm1<<<dim3(128, 8), 256, 0, stream>>>(x, q1w, q1b, k1w, k1b, v1w, v1b, pw,
                                              qA, kA, vT, projb);
    // attn1: D=32, KS=1, grid (16 qg, 16 bh) = 256 blocks x 8 waves; direct h write
    k_attn_v5<32, 0, 1><<<dim3(16, 16), 512, 0, stream>>>(
        qA, kA, vT, h, nullptr, nullptr);
    k_gemm2<<<dim3(128, 6), 256, 0, stream>>>(h, q2w, q2b, k2w, k2b, v2w, v2b,
                                              qA, kA, vT);
    // attn2: D=128, KS=4, grid (16 qg, 4 b, 4 ks) = 256 blocks x 8 waves; partial stores
    k_attn_v5<128, 1, 4><<<dim3(16, 4, 4), 512, 0, stream>>>(
        qA, kA, vT, nullptr, numerb, lpart);
    k_merge2<<<2048, 256, 0, stream>>>(numerb, lpart, projb, lng, lnb, (float*)d_out);
}